// Round 1
// baseline (2230.348 us; speedup 1.0000x reference)
//
#include <hip/hip_runtime.h>

#define B_ 32
#define S_ 64
#define T_ 64
#define H_ 1024
#define V_ 32000

typedef unsigned short u16;
typedef short short8 __attribute__((ext_vector_type(8)));
typedef float f32x4 __attribute__((ext_vector_type(4)));

__device__ inline float bf2f(u16 u) {
    union { unsigned int ui; float f; } c; c.ui = ((unsigned int)u) << 16; return c.f;
}
__device__ inline u16 f2bf(float f) {
    union { float f; unsigned int u; } c; c.f = f;
    unsigned int u = c.u;
    u += 0x7FFFu + ((u >> 16) & 1u);
    return (u16)(u >> 16);
}
__device__ inline float ftanh(float x) {
    float ax = fabsf(x);
    float e = __expf(-2.f * ax);
    float r = (1.f - e) / (1.f + e);
    return copysignf(r, x);
}
__device__ inline float fsigm(float x) { return 1.f / (1.f + __expf(-x)); }

// ---------------------------------------------------------------------------
// Generic 128x128 bf16 MFMA GEMM: C[M=2048,N] = A[2048,K] @ B[N,K]^T + bias
// cmode: 0 = f32 row-major, 1 = logits scatter (m -> t*32+b, write [b,t,v]),
//        2 = bf16 row-major
// ---------------------------------------------------------------------------
__global__ __launch_bounds__(256) void gemm128(
    const u16* __restrict__ A, const u16* __restrict__ Bw,
    const float* __restrict__ bias, void* __restrict__ Cv,
    int N, int K, int cmode)
{
    __shared__ u16 As[128 * 40];
    __shared__ u16 Bs[128 * 40];
    const int tid = threadIdx.x;
    const int n0 = blockIdx.x * 128, m0 = blockIdx.y * 128;
    const int wave = tid >> 6, lane = tid & 63;
    const int wm = wave & 1, wn = wave >> 1;
    const int l16 = lane & 15, qd = lane >> 4;
    f32x4 acc[4][4] = {};

    const int arow = tid >> 1;            // 0..127
    const int akc = (tid & 1) * 16;       // elem offset 0 or 16 within 32-elem row
    const u16* gA = A + (size_t)(m0 + arow) * K + akc;
    const u16* gB = Bw + (size_t)(n0 + arow) * K + akc;

    for (int k0 = 0; k0 < K; k0 += 32) {
        uint4 av0 = *(const uint4*)(gA + k0);
        uint4 av1 = *(const uint4*)(gA + k0 + 8);
        uint4 bv0 = *(const uint4*)(gB + k0);
        uint4 bv1 = *(const uint4*)(gB + k0 + 8);
        __syncthreads();
        *(uint4*)&As[arow * 40 + akc]     = av0;
        *(uint4*)&As[arow * 40 + akc + 8] = av1;
        *(uint4*)&Bs[arow * 40 + akc]     = bv0;
        *(uint4*)&Bs[arow * 40 + akc + 8] = bv1;
        __syncthreads();
        short8 af[4], bfr[4];
#pragma unroll
        for (int i = 0; i < 4; i++)
            af[i] = *(const short8*)&As[(wm * 64 + i * 16 + l16) * 40 + qd * 8];
#pragma unroll
        for (int i = 0; i < 4; i++)
            bfr[i] = *(const short8*)&Bs[(wn * 64 + i * 16 + l16) * 40 + qd * 8];
#pragma unroll
        for (int mi = 0; mi < 4; mi++)
#pragma unroll
            for (int ni = 0; ni < 4; ni++)
                acc[mi][ni] = __builtin_amdgcn_mfma_f32_16x16x32_bf16(
                    af[mi], bfr[ni], acc[mi][ni], 0, 0, 0);
    }

#pragma unroll
    for (int mi = 0; mi < 4; mi++) {
#pragma unroll
        for (int ni = 0; ni < 4; ni++) {
            int ncol = n0 + wn * 64 + ni * 16 + l16;
            float bv = bias ? bias[ncol] : 0.f;
#pragma unroll
            for (int r = 0; r < 4; r++) {
                int mrow = m0 + wm * 64 + mi * 16 + qd * 4 + r;
                float v = acc[mi][ni][r] + bv;
                if (cmode == 0) {
                    ((float*)Cv)[(size_t)mrow * N + ncol] = v;
                } else if (cmode == 1) {
                    int tt = mrow >> 5, bb = mrow & 31;
                    ((float*)Cv)[((size_t)bb * T_ + tt) * V_ + ncol] = v;
                } else {
                    ((u16*)Cv)[(size_t)mrow * N + ncol] = f2bf(v);
                }
            }
        }
    }
}

// ---------------------------------------------------------------------------
// Per-step M=32 GEMM: qg[32,4096] = hB[32,1024] @ Wcat[4096,1024]^T + bcat
// grid 64 blocks x 256 threads; wave w handles 16-col slice
// ---------------------------------------------------------------------------
__global__ __launch_bounds__(256) void gemm_qg(
    const u16* __restrict__ hB, const u16* __restrict__ Wcat,
    const float* __restrict__ bcat, float* __restrict__ qg)
{
    __shared__ u16 As[32 * 72];
    __shared__ u16 Bs[64 * 72];
    const int tid = threadIdx.x;
    const int n0 = blockIdx.x * 64;
    const int wave = tid >> 6, lane = tid & 63;
    const int l16 = lane & 15, qd = lane >> 4;
    f32x4 acc[2] = {};

    const int arow = tid >> 3, akc = (tid & 7) * 8;   // 32 rows x 8 chunks of 8
    const int brow = tid >> 2, bkc = (tid & 3) * 16;  // 64 rows x 2 chunks of 16
    const u16* gA = hB + (size_t)arow * H_ + akc;
    const u16* gB = Wcat + (size_t)(n0 + brow) * H_ + bkc;

    for (int k0 = 0; k0 < H_; k0 += 64) {
        uint4 av  = *(const uint4*)(gA + k0);
        uint4 bv0 = *(const uint4*)(gB + k0);
        uint4 bv1 = *(const uint4*)(gB + k0 + 8);
        __syncthreads();
        *(uint4*)&As[arow * 72 + akc]     = av;
        *(uint4*)&Bs[brow * 72 + bkc]     = bv0;
        *(uint4*)&Bs[brow * 72 + bkc + 8] = bv1;
        __syncthreads();
#pragma unroll
        for (int ks = 0; ks < 2; ks++) {
            short8 bf = *(const short8*)&Bs[(wave * 16 + l16) * 72 + ks * 32 + qd * 8];
#pragma unroll
            for (int mi = 0; mi < 2; mi++) {
                short8 af = *(const short8*)&As[(mi * 16 + l16) * 72 + ks * 32 + qd * 8];
                acc[mi] = __builtin_amdgcn_mfma_f32_16x16x32_bf16(af, bf, acc[mi], 0, 0, 0);
            }
        }
    }
#pragma unroll
    for (int mi = 0; mi < 2; mi++) {
#pragma unroll
        for (int r = 0; r < 4; r++) {
            int m = mi * 16 + qd * 4 + r;
            int n = n0 + wave * 16 + l16;
            qg[(size_t)m * 4096 + n] = acc[mi][r] + bcat[n];
        }
    }
}

// ---------------------------------------------------------------------------
// scores[b,s] = Va . tanh(q[b] + Uk[b,s]) + Va_b ; 2048 wave-units
// ---------------------------------------------------------------------------
__global__ __launch_bounds__(256) void k_scores(
    const float* __restrict__ qg, const float* __restrict__ Uk,
    const float* __restrict__ Va_w, const float* __restrict__ Va_b,
    float* __restrict__ sc)
{
    const int tid = threadIdx.x;
    const int wave = tid >> 6, lane = tid & 63;
    const int gw = blockIdx.x * 4 + wave;
#pragma unroll
    for (int uu = 0; uu < 2; uu++) {
        int u = gw * 2 + uu;
        int b = u >> 6, s = u & 63;
        const float* q = qg + (size_t)b * 4096;
        const float* uk = Uk + (size_t)(b * S_ + s) * H_;
        float p = 0.f;
#pragma unroll 4
        for (int i = 0; i < 16; i++) {
            int h = lane + i * 64;
            p += Va_w[h] * ftanh(q[h] + uk[h]);
        }
#pragma unroll
        for (int m = 1; m < 64; m <<= 1) p += __shfl_xor(p, m);
        if (lane == 0) sc[u] = p + Va_b[0];
    }
}

// ---------------------------------------------------------------------------
// softmax (redundant per g) + gi_c via E2 + GRU gates + h update
// grid 256: block = (b = blk>>3, g = blk&7), g owns j0 = g*128 + tid (tid<128)
// ---------------------------------------------------------------------------
__global__ __launch_bounds__(256) void k_gru(
    int t,
    const float* __restrict__ sc, const u16* __restrict__ E2,
    const float* __restrict__ gix, const float* __restrict__ qg,
    float* __restrict__ hstate, u16* __restrict__ hB,
    u16* __restrict__ Hall, float* __restrict__ out_attn,
    float* __restrict__ out_hT)
{
    __shared__ float wl[64];
    const int tid = threadIdx.x;
    const int b = blockIdx.x >> 3, g = blockIdx.x & 7;
    if (tid < 64) {
        float x = sc[b * S_ + tid];
        float mx = x;
#pragma unroll
        for (int m = 1; m < 64; m <<= 1) mx = fmaxf(mx, __shfl_xor(mx, m));
        float e = __expf(x - mx);
        float ssum = e;
#pragma unroll
        for (int m = 1; m < 64; m <<= 1) ssum += __shfl_xor(ssum, m);
        float w = e / ssum;
        wl[tid] = w;
        if (g == 0) out_attn[(size_t)b * T_ * S_ + (size_t)t * S_ + tid] = w;
    }
    __syncthreads();
    if (tid < 128) {
        int j = g * 128 + tid;
        float ar = 0.f, az = 0.f, an = 0.f;
        const u16* e2 = E2 + (size_t)b * S_ * 3072;
        for (int s = 0; s < 64; s++) {
            float w = wl[s];
            const u16* row = e2 + (size_t)s * 3072;
            ar += w * bf2f(row[j]);
            az += w * bf2f(row[1024 + j]);
            an += w * bf2f(row[2048 + j]);
        }
        const size_t m = (size_t)t * B_ + b;
        const float* gi = gix + m * 3072;
        const float* gh = qg + (size_t)b * 4096 + 1024;
        float r = fsigm(ar + gi[j] + gh[j]);
        float z = fsigm(az + gi[1024 + j] + gh[1024 + j]);
        float n = ftanh(an + gi[2048 + j] + r * gh[2048 + j]);
        float hp = hstate[b * H_ + j];
        float hn = (1.f - z) * n + z * hp;
        hstate[b * H_ + j] = hn;
        hB[b * H_ + j] = f2bf(hn);
        Hall[m * H_ + j] = f2bf(hn);
        out_hT[b * H_ + j] = hn;
    }
}

// ---------------------------------------------------------------------------
// prologue helpers
// ---------------------------------------------------------------------------
__global__ __launch_bounds__(256) void k_gather(
    const float* __restrict__ emb, const int* __restrict__ target,
    u16* __restrict__ XB)
{
    int m = blockIdx.x;           // 0..2047, m = t*32+b
    int t = m >> 5, b = m & 31;
    int tok = (t == 0) ? 1 : target[b * T_ + (t - 1)];
    float4 v = ((const float4*)(emb + (size_t)tok * H_))[threadIdx.x];
    ushort4 o = { f2bf(v.x), f2bf(v.y), f2bf(v.z), f2bf(v.w) };
    *(ushort4*)&XB[(size_t)m * H_ + threadIdx.x * 4] = o;
}

__global__ __launch_bounds__(256) void k_f2b(
    const float* __restrict__ src, u16* __restrict__ dst, int n4)
{
    int i = blockIdx.x * 256 + threadIdx.x;
    int stride = gridDim.x * 256;
    for (; i < n4; i += stride) {
        float4 v = ((const float4*)src)[i];
        ushort4 o = { f2bf(v.x), f2bf(v.y), f2bf(v.z), f2bf(v.w) };
        ((ushort4*)dst)[i] = o;
    }
}

__global__ __launch_bounds__(256) void k_split(
    const float* __restrict__ W, u16* __restrict__ Wx, u16* __restrict__ Wc)
{
    const int n4 = 3072 * 512;    // W_ih is [3072, 2048] -> 512 float4 per row
    int i = blockIdx.x * 256 + threadIdx.x;
    int stride = gridDim.x * 256;
    for (; i < n4; i += stride) {
        int row = i >> 9;
        int c4 = i & 511;
        float4 v = ((const float4*)W)[i];
        ushort4 o = { f2bf(v.x), f2bf(v.y), f2bf(v.z), f2bf(v.w) };
        if (c4 < 256) *(ushort4*)&Wx[(size_t)row * H_ + c4 * 4] = o;
        else          *(ushort4*)&Wc[(size_t)row * H_ + (c4 - 256) * 4] = o;
    }
}

__global__ __launch_bounds__(256) void k_misc(
    const float* __restrict__ Wa_b, const float* __restrict__ b_hh,
    const float* __restrict__ ehid, float* __restrict__ bcat,
    float* __restrict__ hstate, u16* __restrict__ hB)
{
    int i = blockIdx.x * 256 + threadIdx.x;   // grid 128 -> 32768 threads
    if (i < 4096) bcat[i] = (i < 1024) ? Wa_b[i] : b_hh[i - 1024];
    if (i < 32768) {
        float v = ehid[i];
        hstate[i] = v;
        hB[i] = f2bf(v);
    }
}

// ---------------------------------------------------------------------------
extern "C" void kernel_launch(void* const* d_in, const int* in_sizes, int n_in,
                              void* d_out, int out_size, void* d_ws, size_t ws_size,
                              hipStream_t stream)
{
    const float* enc   = (const float*)d_in[0];
    const float* ehid  = (const float*)d_in[1];
    const int*   tgt   = (const int*)d_in[2];
    const float* emb   = (const float*)d_in[3];
    const float* Wa_w  = (const float*)d_in[4];
    const float* Wa_b  = (const float*)d_in[5];
    const float* Ua_w  = (const float*)d_in[6];
    const float* Ua_b  = (const float*)d_in[7];
    const float* Va_w  = (const float*)d_in[8];
    const float* Va_b  = (const float*)d_in[9];
    const float* W_ih  = (const float*)d_in[10];
    const float* W_hh  = (const float*)d_in[11];
    const float* b_ih  = (const float*)d_in[12];
    const float* b_hh  = (const float*)d_in[13];
    const float* out_w = (const float*)d_in[14];
    const float* out_b = (const float*)d_in[15];

    char* ws = (char*)d_ws;
    size_t off = 0;
    auto alloc = [&](size_t bytes) {
        void* p = ws + off;
        off += (bytes + 255) & ~(size_t)255;
        return p;
    };
    u16* outB  = (u16*)alloc((size_t)V_ * H_ * 2);
    u16* encB  = (u16*)alloc((size_t)B_ * S_ * H_ * 2);
    u16* UaB   = (u16*)alloc((size_t)H_ * H_ * 2);
    u16* WxB   = (u16*)alloc((size_t)3 * H_ * H_ * 2);
    u16* WcB   = (u16*)alloc((size_t)3 * H_ * H_ * 2);
    u16* WcatB = (u16*)alloc((size_t)4 * H_ * H_ * 2);
    u16* XB    = (u16*)alloc((size_t)T_ * B_ * H_ * 2);
    u16* Hall  = (u16*)alloc((size_t)T_ * B_ * H_ * 2);
    u16* hB    = (u16*)alloc((size_t)B_ * H_ * 2);
    u16* E2    = (u16*)alloc((size_t)B_ * S_ * 3 * H_ * 2);
    float* Uk     = (float*)alloc((size_t)B_ * S_ * H_ * 4);
    float* gix    = (float*)alloc((size_t)T_ * B_ * 3 * H_ * 4);
    float* qg     = (float*)alloc((size_t)B_ * 4 * H_ * 4);
    float* hstate = (float*)alloc((size_t)B_ * H_ * 4);
    float* bcat   = (float*)alloc((size_t)4 * H_ * 4);
    float* sc     = (float*)alloc((size_t)B_ * S_ * 4);

    float* out_logits = (float*)d_out;
    float* out_hT     = out_logits + (size_t)B_ * T_ * V_;
    float* out_attn   = out_hT + (size_t)B_ * H_;

    // --- prologue: conversions / gathers ---
    k_f2b<<<512, 256, 0, stream>>>(out_w, outB, V_ * H_ / 4);
    k_f2b<<<256, 256, 0, stream>>>(enc, encB, B_ * S_ * H_ / 4);
    k_f2b<<<128, 256, 0, stream>>>(Ua_w, UaB, H_ * H_ / 4);
    k_split<<<512, 256, 0, stream>>>(W_ih, WxB, WcB);
    k_f2b<<<128, 256, 0, stream>>>(Wa_w, WcatB, H_ * H_ / 4);
    k_f2b<<<256, 256, 0, stream>>>(W_hh, WcatB + (size_t)H_ * H_, 3 * H_ * H_ / 4);
    k_gather<<<2048, 256, 0, stream>>>(emb, tgt, XB);
    k_misc<<<128, 256, 0, stream>>>(Wa_b, b_hh, ehid, bcat, hstate, hB);

    // --- prologue GEMMs (M = 2048 in all cases) ---
    gemm128<<<dim3(H_ / 128, 16), 256, 0, stream>>>(encB, UaB, Ua_b, (void*)Uk, H_, H_, 0);
    gemm128<<<dim3(3 * H_ / 128, 16), 256, 0, stream>>>(encB, WcB, (const float*)nullptr, (void*)E2, 3 * H_, H_, 2);
    gemm128<<<dim3(3 * H_ / 128, 16), 256, 0, stream>>>(XB, WxB, b_ih, (void*)gix, 3 * H_, H_, 0);

    // --- sequential decode loop ---
    for (int t = 0; t < T_; t++) {
        gemm_qg<<<64, 256, 0, stream>>>(hB, WcatB, bcat, qg);
        k_scores<<<256, 256, 0, stream>>>(qg, Uk, Va_w, Va_b, sc);
        k_gru<<<256, 256, 0, stream>>>(t, sc, E2, gix, qg, hstate, hB, Hall, out_attn, out_hT);
    }

    // --- batched logits GEMM: [2048,1024] @ [32000,1024]^T -> scatter [B,T,V] ---
    gemm128<<<dim3(V_ / 128, 16), 256, 0, stream>>>(Hall, outB, out_b, (void*)out_logits, V_, H_, 1);
}